// Round 4
// baseline (91.374 us; speedup 1.0000x reference)
//
#include <hip/hip_runtime.h>

// Signature kernel (dyadic order 1, sigma=1) for xs:(16,128,8), ys:(16,128,8) f32.
// One block (256 thr) per pair. Phase 1 (all 4 waves): RBF Gram K (128x128, f32) and
// quarter-scaled 2nd mixed difference in-place in LDS (stride 128, col 127 zeroed).
// Phase 2 (wave 0 only, ZERO barriers): Goursat PDE on the 255x255 refined grid as a
// register wavefront: lane l owns rows 4l+1..4l+4, all at column j = s - 2*l per step.
// Cross-lane handoff via one __shfl_up(f32) per step + 3-deep register FIFO (skew 2
// gives the shuffle 2 steps of slack). Out-of-range columns read B[127] == 0
// (broadcast) -> inc=0 -> k11 = k10+k01-k00 keeps boundary 1s alive: no predication.
// PDE arithmetic in f32 (round-3 showed the active SIMD is ISSUE-bound; f64 ops cost
// >=2x issue cycles). Expected extra f32 accumulation error ~1e-3 << threshold.

#define LX 128
#define D  8
#define NB 16
#define NBODY 190        // 190 double-steps = s = 1..380 ; result at s = 380

__global__ __launch_bounds__(256)
void sigkernel_kernel(const float* __restrict__ xs,
                      const float* __restrict__ ys,
                      float* __restrict__ out)
{
    __shared__ float sx[LX][D + 1];
    __shared__ float sy[LX][D + 1];
    __shared__ float xsqv[LX];
    __shared__ float ysqv[LX];
    __shared__ float B[LX * LX + 132];   // K (stride 128) then 0.25*diff; +pad for OOB-safe diff reads

    const int t  = threadIdx.x;
    const int bx = blockIdx.x;
    const int by = blockIdx.y;
    const float* xp = xs + bx * (LX * D);
    const float* yp = ys + by * (LX * D);

    // ---- load x, y ----
    for (int e = t; e < LX * D; e += 256) {
        sx[e >> 3][e & 7] = xp[e];
        sy[e >> 3][e & 7] = yp[e];
    }
    __syncthreads();

    // ---- squared norms ----
    if (t < LX) {
        float sxx = 0.f, syy = 0.f;
        #pragma unroll
        for (int k = 0; k < D; ++k) {
            sxx += sx[t][k] * sx[t][k];
            syy += sy[t][k] * sy[t][k];
        }
        xsqv[t] = sxx;
        ysqv[t] = syy;
    }
    __syncthreads();

    // ---- K[i][j] = exp(-0.5*(|x_i|^2+|y_j|^2-2 x_i.y_j)), stride 128 ----
    {
        const int j = t & 127;
        float yr[D];
        #pragma unroll
        for (int k = 0; k < D; ++k) yr[k] = sy[j][k];
        const float ysq = ysqv[j];
        #pragma unroll
        for (int c = 0; c < 64; ++c) {
            const int e = t + c * 256;
            const int i = e >> 7;
            float dot = 0.f;
            #pragma unroll
            for (int k = 0; k < D; ++k) dot += sx[i][k] * yr[k];
            const float sq = xsqv[i] + ysq - 2.0f * dot;
            B[e] = expf(-0.5f * sq);
        }
    }
    __syncthreads();

    // ---- quarter-scaled 2nd mixed diff, in place at stride 128 (no int division) ----
    // cell (i,j) valid for i<127 && j<127; i==127 / j==127 lanes read padded garbage
    // and discard. Afterwards col 127 of rows 0..126 is zeroed (clamp target).
    {
        float rv[64];
        #pragma unroll
        for (int c = 0; c < 64; ++c) {
            const int e = t + c * 256;
            rv[c] = 0.25f * (B[e + 129] + B[e] - B[e + 128] - B[e + 1]);
        }
        __syncthreads();
        #pragma unroll
        for (int c = 0; c < 64; ++c) {
            const int e = t + c * 256;
            const int i = e >> 7, j = e & 127;
            if (i < 127 && j < 127) B[e] = rv[c];
        }
        if (t < 127) B[t * 128 + 127] = 0.f;
    }
    __syncthreads();

    // ---- waves 1..3 done; wave 0 runs the register wavefront (no more barriers) ----
    if (t >= 64) return;

    const int l = t;
    const int rowa = 2 * l;                               // dyadic row for rows 4l+1, 4l+2
    const int rowb = (2 * l + 1 > 126) ? 126 : 2 * l + 1; // rows 4l+3, 4l+4 (lane 63 dummy)
    const int baseA = rowa * 128;
    const int baseB = rowb * 128;
    const bool lane0 = (l == 0);

    float cur0 = 1.f, cur1 = 1.f, cur2 = 1.f, cur3 = 1.f;  // rows 4l+1..4l+4, col j-1
    float h0 = 1.f, h1 = 1.f, h2 = 1.f;                    // neighbor row-4l history

    // prefetch body 0: q(body k) = k - l ; OOB -> B[127] == 0
    float inA, inB;
    {
        const int q = -l;
        const bool cl = ((unsigned)q > 126u);
        inA = B[cl ? 127 : (baseA + q)];
        inB = B[cl ? 127 : (baseB + q)];
    }

    #pragma unroll 2
    for (int k = 0; k < NBODY; ++k) {
        // coefficients for this body's dyadic cells (q = k - l), from prefetched inc
        const float ia = inA;
        const float ib = inB;
        const float ea = ia * ia * (1.0f / 12.0f);
        const float eb = ib * ib * (1.0f / 12.0f);
        const float c1a = 1.0f + 0.5f * ia + ea, c2a = 1.0f - ea;
        const float c1b = 1.0f + 0.5f * ib + eb, c2b = 1.0f - eb;

        // prefetch next body (~1 body of slack hides LDS latency)
        {
            const int qn = k + 1 - l;
            const bool cl = ((unsigned)qn > 126u);
            inA = B[cl ? 127 : (baseA + qn)];
            inB = B[cl ? 127 : (baseB + qn)];
        }

        #pragma unroll
        for (int sub = 0; sub < 2; ++sub) {
            // start of step s: h1 = K[4l][j], h2 = K[4l][j-1] (lane0: always 1)
            const float n0 = (h1 + cur0) * c1a - h2   * c2a;
            const float n1 = (n0 + cur1) * c1a - cur0 * c2a;
            const float n2 = (n1 + cur2) * c1b - cur1 * c2b;
            const float n3 = (n2 + cur3) * c1b - cur2 * c2b;
            cur0 = n0; cur1 = n1; cur2 = n2; cur3 = n3;
            const float sh = __shfl_up(n3, 1);
            h2 = h1; h1 = h0; h0 = lane0 ? 1.0f : sh;
        }
    }

    // K[254][254]: row 254 = lane 63's second row, finished at s = 380
    if (l == 63) out[bx * NB + by] = cur1;
}

extern "C" void kernel_launch(void* const* d_in, const int* in_sizes, int n_in,
                              void* d_out, int out_size, void* d_ws, size_t ws_size,
                              hipStream_t stream)
{
    const float* xs = (const float*)d_in[0];
    const float* ys = (const float*)d_in[1];
    float* out = (float*)d_out;
    dim3 grid(NB, NB);
    dim3 block(256);
    hipLaunchKernelGGL(sigkernel_kernel, grid, block, 0, stream, xs, ys, out);
}

// Round 5
// 84.993 us; speedup vs baseline: 1.0751x; 1.0751x over previous
//
#include <hip/hip_runtime.h>

// Signature kernel (dyadic order 1, sigma=1) for xs:(16,128,8), ys:(16,128,8) f32.
// One block (256 thr) per pair. Phase 1 (all 4 waves): RBF Gram K (128x128, f32) and
// quarter-scaled 2nd mixed difference in-place in LDS (stride 128, col 127 zeroed).
// Phase 2 (wave 0 only, ZERO barriers): Goursat PDE on the 255x255 refined grid as a
// register wavefront: lane l owns rows 4l+1..4l+4, all at column j = s - 2*l per step.
// Cross-lane handoff via DPP wave_shr1 (VALU pipe, ~4cy, lane0 gets old=1.0 free) --
// round 4 showed the old __shfl_up (ds_bpermute) + mixed DS queue serialized ~3 LDS
// latencies per body (~450cy/body ~= the whole 36us of phase 2). inc prefetch now
// runs 2 bodies ahead in a clean DS queue so counted lgkmcnt hides the ~120cy reads.
// PDE arithmetic in f32 (absmax identical to f64 at round 4).

#define LX 128
#define D  8
#define NB 16
#define NBODY 190        // 190 double-steps = s = 1..380 ; result at s = 380

__device__ __forceinline__ float wave_shr1_or_one(float v) {
    // lane i <- v[lane i-1]; lane 0 <- 1.0f (bound_ctrl=0 keeps 'old' operand)
    const int one = 0x3f800000;
    int r = __builtin_amdgcn_update_dpp(one, __float_as_int(v),
                                        0x138 /*wave_shr:1*/, 0xF, 0xF, false);
    return __int_as_float(r);
}

__global__ __launch_bounds__(256)
void sigkernel_kernel(const float* __restrict__ xs,
                      const float* __restrict__ ys,
                      float* __restrict__ out)
{
    __shared__ float sx[LX][D + 1];
    __shared__ float sy[LX][D + 1];
    __shared__ float xsqv[LX];
    __shared__ float ysqv[LX];
    __shared__ float B[LX * LX + 132];   // K (stride 128) then 0.25*diff; +pad for OOB diff reads

    const int t  = threadIdx.x;
    const int bx = blockIdx.x;
    const int by = blockIdx.y;
    const float* xp = xs + bx * (LX * D);
    const float* yp = ys + by * (LX * D);

    // ---- load x, y ----
    for (int e = t; e < LX * D; e += 256) {
        sx[e >> 3][e & 7] = xp[e];
        sy[e >> 3][e & 7] = yp[e];
    }
    __syncthreads();

    // ---- squared norms ----
    if (t < LX) {
        float sxx = 0.f, syy = 0.f;
        #pragma unroll
        for (int k = 0; k < D; ++k) {
            sxx += sx[t][k] * sx[t][k];
            syy += sy[t][k] * sy[t][k];
        }
        xsqv[t] = sxx;
        ysqv[t] = syy;
    }
    __syncthreads();

    // ---- K[i][j] = exp(-0.5*(|x_i|^2+|y_j|^2-2 x_i.y_j)), stride 128 ----
    {
        const int j = t & 127;
        float yr[D];
        #pragma unroll
        for (int k = 0; k < D; ++k) yr[k] = sy[j][k];
        const float ysq = ysqv[j];
        #pragma unroll
        for (int c = 0; c < 64; ++c) {
            const int e = t + c * 256;
            const int i = e >> 7;
            float dot = 0.f;
            #pragma unroll
            for (int k = 0; k < D; ++k) dot += sx[i][k] * yr[k];
            const float sq = xsqv[i] + ysq - 2.0f * dot;
            B[e] = expf(-0.5f * sq);
        }
    }
    __syncthreads();

    // ---- quarter-scaled 2nd mixed diff, in place at stride 128 (no int division) ----
    {
        float rv[64];
        #pragma unroll
        for (int c = 0; c < 64; ++c) {
            const int e = t + c * 256;
            rv[c] = 0.25f * (B[e + 129] + B[e] - B[e + 128] - B[e + 1]);
        }
        __syncthreads();
        #pragma unroll
        for (int c = 0; c < 64; ++c) {
            const int e = t + c * 256;
            const int i = e >> 7, j = e & 127;
            if (i < 127 && j < 127) B[e] = rv[c];
        }
        if (t < 127) B[t * 128 + 127] = 0.f;   // zero word: OOB clamp target
    }
    __syncthreads();

    // ---- waves 1..3 done; wave 0 runs the register wavefront (no more barriers) ----
    if (t >= 64) return;

    const int l = t;
    const int rowa = 2 * l;                               // dyadic row for rows 4l+1, 4l+2
    const int rowb = (2 * l + 1 > 126) ? 126 : 2 * l + 1; // rows 4l+3, 4l+4 (lane 63 dummy)
    const int baseA = rowa * 128;
    const int baseB = rowb * 128;

    float cur0 = 1.f, cur1 = 1.f, cur2 = 1.f, cur3 = 1.f;  // rows 4l+1..4l+4, col j-1
    float h0 = 1.f, h1 = 1.f, h2 = 1.f;                    // neighbor row-4l history

    // prefetch bodies 0 and 1: q(body k) = k - l ; OOB -> B[..127] == 0
    float iA0, iB0, iA1, iB1;
    {
        int q = -l;
        bool cl = ((unsigned)q > 126u);
        iA0 = B[cl ? 127 : (baseA + q)];
        iB0 = B[cl ? 127 : (baseB + q)];
        q = 1 - l;
        cl = ((unsigned)q > 126u);
        iA1 = B[cl ? 127 : (baseA + q)];
        iB1 = B[cl ? 127 : (baseB + q)];
    }

    #pragma unroll 2
    for (int k = 0; k < NBODY; ++k) {
        // coefficients for this body's dyadic cells (q = k - l)
        const float ia = iA0;
        const float ib = iB0;
        const float ea = ia * ia * (1.0f / 12.0f);
        const float eb = ib * ib * (1.0f / 12.0f);
        const float c1a = 1.0f + 0.5f * ia + ea, c2a = 1.0f - ea;
        const float c1b = 1.0f + 0.5f * ib + eb, c2b = 1.0f - eb;

        // prefetch body k+2 (2 bodies of slack; clean DS queue -> counted lgkmcnt)
        {
            const int qn = k + 2 - l;
            const bool cl = ((unsigned)qn > 126u);
            iA0 = B[cl ? 127 : (baseA + qn)];
            iB0 = B[cl ? 127 : (baseB + qn)];
        }
        // rotate: iA0 <- body k+1, iA1 <- body k+2 (pure renaming under unroll 2)
        { float tv = iA0; iA0 = iA1; iA1 = tv;
          tv = iB0; iB0 = iB1; iB1 = tv; }

        #pragma unroll
        for (int sub = 0; sub < 2; ++sub) {
            // start of step s: h1 = K[4l][j], h2 = K[4l][j-1] (lane0: always 1)
            const float n0 = (h1 + cur0) * c1a - h2   * c2a;
            const float n1 = (n0 + cur1) * c1a - cur0 * c2a;
            const float n2 = (n1 + cur2) * c1b - cur1 * c2b;
            const float n3 = (n2 + cur3) * c1b - cur2 * c2b;
            cur0 = n0; cur1 = n1; cur2 = n2; cur3 = n3;
            const float sh = wave_shr1_or_one(n3);   // VALU DPP, no lgkmcnt
            h2 = h1; h1 = h0; h0 = sh;
        }
    }

    // K[254][254]: row 254 = lane 63's second row, finished at s = 380
    if (l == 63) out[bx * NB + by] = cur1;
}

extern "C" void kernel_launch(void* const* d_in, const int* in_sizes, int n_in,
                              void* d_out, int out_size, void* d_ws, size_t ws_size,
                              hipStream_t stream)
{
    const float* xs = (const float*)d_in[0];
    const float* ys = (const float*)d_in[1];
    float* out = (float*)d_out;
    dim3 grid(NB, NB);
    dim3 block(256);
    hipLaunchKernelGGL(sigkernel_kernel, grid, block, 0, stream, xs, ys, out);
}